// Round 16
// baseline (1280.991 us; speedup 1.0000x reference)
//
#include <hip/hip_runtime.h>
#include <math.h>

#define VOCABSZ 32000
#define EMBD 512
#define HIDD 512
#define BSZ 32
#define TLEN 32
#define G4 2048
#define NGRP 1000            // wot col-groups of 32
#define NLB 500              // logits blocks / partial slots
#define SSTRIDE 512          // part slot stride per row
#define PSTRIDE 16384        // part SoA array stride (32 rows * 512)
#define SW 256.0f            // Wo fp8 scale
#define SH 16.0f             // h fp8 scale
#define INV_SWH (1.0f / (SW * SH))

using bf16x8 = __attribute__((ext_vector_type(8))) short;
using f32x16 = __attribute__((ext_vector_type(16))) float;
typedef long long i64;

__device__ __forceinline__ float sigmoidf_(float x) { return 1.f / (1.f + expf(-x)); }
__device__ __forceinline__ unsigned short f2bf(float f) {
    unsigned u = __float_as_uint(f);
    return (unsigned short)((u + 0x7fffu + ((u >> 16) & 1u)) >> 16);   // RNE
}
// float -> OCP e4m3fn, RNE, FTZ for |x| < 2^-6 (negligible for our data)
__device__ __forceinline__ unsigned char f2e4m3(float f) {
    unsigned u = __float_as_uint(f);
    unsigned s = (u >> 24) & 0x80u;
    int e = (int)((u >> 23) & 0xffu);
    unsigned m = u & 0x7fffffu;
    int ee = e - 120;                    // e4m3 biased exponent
    if (ee >= 16) return (unsigned char)(s | 0x7E);   // saturate to 448
    if (ee <= 0) return (unsigned char)s;             // FTZ
    unsigned r = m + 0x7FFFFu + ((m >> 20) & 1u);     // RNE to 3 mant bits
    if (r & 0x800000u) { ee += 1; r = 0; if (ee >= 16) return (unsigned char)(s | 0x7E); }
    unsigned mant = (r >> 20) & 7u;
    if (ee == 15 && mant == 7u) return (unsigned char)(s | 0x7E);  // avoid NaN enc
    return (unsigned char)(s | (unsigned)(ee << 3) | mant);
}

// ---------------------------------------------------------------------------
// init7 (R15-verified): 64 blocks x 256 thr; block 0 probes coin + ce_acc.
// ---------------------------------------------------------------------------
__global__ __launch_bounds__(256) void init7_kernel(
    const float* __restrict__ x, const void* __restrict__ coin,
    float* __restrict__ cst, unsigned short* __restrict__ hbf,
    unsigned char* __restrict__ hf8,
    float* __restrict__ ce_acc, int* __restrict__ flag) {
    __shared__ int s_f;
    int tid = threadIdx.x;
    int i = blockIdx.x * 256 + tid;
    if (blockIdx.x == 0) {
        if (tid == 0) s_f = 0;
        __syncthreads();
        // coin dtype probe: uint8 bools pack to words like 0x00010001 (>1)
        if (((const unsigned int*)coin)[tid] > 1u) s_f = 1;
        __syncthreads();
        if (tid == 0) *flag = s_f;
        if (tid < 32) ce_acc[tid] = 0.f;
    }
    float v = x[i];
    cst[i] = 0.f;
    hbf[i] = f2bf(v);
    hf8[i] = f2e4m3(v * SH);
}

// ---------------------------------------------------------------------------
// emb_prep (R14-verified): emb fp32 -> bf16 same layout.
// ---------------------------------------------------------------------------
__global__ __launch_bounds__(256) void emb_prep_kernel(
    const float* __restrict__ emb, unsigned short* __restrict__ embbf) {
    size_t i8 = ((size_t)blockIdx.x * 256 + threadIdx.x) * 8;
    float4 a = *(const float4*)&emb[i8];
    float4 b = *(const float4*)&emb[i8 + 4];
    bf16x8 v;
    v[0] = (short)f2bf(a.x); v[1] = (short)f2bf(a.y);
    v[2] = (short)f2bf(a.z); v[3] = (short)f2bf(a.w);
    v[4] = (short)f2bf(b.x); v[5] = (short)f2bf(b.y);
    v[6] = (short)f2bf(b.z); v[7] = (short)f2bf(b.w);
    *(bf16x8*)&embbf[i8] = v;
}

// ---------------------------------------------------------------------------
// wot8_prep (R15-verified): Wo -> e4m3(Wo*SW), B-frag order, PAIRED-kt:
//   flat idx = (kt>>1)*128 + lane*2 + (kt&1)  (per col-group g)
// ---------------------------------------------------------------------------
__global__ __launch_bounds__(256) void wot8_prep_kernel(
    const float* __restrict__ Wo, i64* __restrict__ wot8) {
    __shared__ unsigned char s[512 * 32];      // [k][col] 16 KB
    int g = blockIdx.x;
    int tid = threadIdx.x;
    int col = tid & 31;
    int k0 = tid >> 5;
    for (int kk = k0; kk < 512; kk += 8)
        s[kk * 32 + col] = f2e4m3(Wo[(size_t)kk * VOCABSZ + g * 32 + col] * SW);
    __syncthreads();
    for (int f = tid; f < 2048; f += 256) {
        int kt = f >> 6, lane = f & 63;
        int kb = kt * 16 + ((lane >> 5) << 3);
        int c = lane & 31;
        union { unsigned char b[8]; i64 v; } u;
        #pragma unroll
        for (int j = 0; j < 8; ++j) u.b[j] = s[(kb + j) * 32 + c];
        wot8[(size_t)g * 2048 + (kt >> 1) * 128 + lane * 2 + (kt & 1)] = u.v;
    }
}

// ---------------------------------------------------------------------------
// wcell_prep (R11-R15 verified): Wi/Wh -> bf16 B-frag order block-packed.
// ---------------------------------------------------------------------------
__global__ __launch_bounds__(256) void wcell_prep_kernel(
    const float* __restrict__ Wi, const float* __restrict__ Wh,
    unsigned short* __restrict__ wcell) {
    __shared__ unsigned short s[512 * 32];     // [kl][lc] 32 KB
    int cb = blockIdx.x >> 1;
    int half = blockIdx.x & 1;
    const float* Wsrc = half ? Wh : Wi;
    int tid = threadIdx.x;
    int lc = tid & 31;
    int gcol = (lc >> 3) * 512 + cb * 8 + (lc & 7);
    int k0 = tid >> 5;
    for (int kl = k0; kl < 512; kl += 8)
        s[kl * 32 + lc] = f2bf(Wsrc[(size_t)kl * G4 + gcol]);
    __syncthreads();
    bf16x8* out8 = (bf16x8*)wcell;
    for (int f = tid; f < 2048; f += 256) {
        int ktl = f >> 6, lane = f & 63;
        int kb = ktl * 16 + ((lane >> 5) << 3);
        int c = lane & 31;
        bf16x8 v;
        #pragma unroll
        for (int j = 0; j < 8; ++j) v[j] = (short)s[(kb + j) * 32 + c];
        out8[((size_t)cb * 64 + half * 32 + ktl) * 64 + lane] = v;
    }
}

// ---------------------------------------------------------------------------
// cell_mfma4 (R14/R15-verified; slot constants now 500/512-stride).
// 64 blocks x 1024 thr (16 waves).
// ---------------------------------------------------------------------------
__global__ __launch_bounds__(1024) void cell_mfma4_kernel(
    const float* __restrict__ emb, const unsigned short* __restrict__ embbf,
    const int* __restrict__ labels,
    const void* __restrict__ coin, const int* __restrict__ flag,
    const unsigned short* __restrict__ wcell, const float* __restrict__ bias,
    float* __restrict__ cst, unsigned short* __restrict__ hbf,
    unsigned char* __restrict__ hf8,
    const float* __restrict__ part, float* __restrict__ ce_acc, int t) {
    __shared__ float sg[16][32][32];    // 64 KB [wave][row][lc]
    __shared__ float st[32][33];        // combined gates
    __shared__ int s_tok[32];
    int tid = threadIdx.x;
    int cb = blockIdx.x;
    int lane = tid & 63, wv = tid >> 6;

    // ---- PHASE A ----
    if (t == 0) {
        if (tid < 32) s_tok[tid] = 1;            // START
    } else {
        int row = tid >> 5, slot = tid & 31;
        int tm1 = t - 1;
        float m = -3.0e38f; int mi = 0;
        for (int ib = slot; ib < NLB; ib += 32) {
            int e = row * SSTRIDE + ib;
            float pm = part[e];
            int pi = __float_as_int(part[2 * PSTRIDE + e]);
            if (pm > m || (pm == m && pi < mi)) { m = pm; mi = pi; }
        }
        #pragma unroll
        for (int d = 1; d < 32; d <<= 1) {
            float om = __shfl_xor(m, d);
            int omi = __shfl_xor(mi, d);
            if (om > m || (om == m && omi < mi)) { m = om; mi = omi; }
        }
        if (slot == 0) {
            int lab = labels[row * TLEN + tm1];
            int cn = (*flag) ? (int)((const unsigned char*)coin)[row * TLEN + tm1]
                             : ((const int*)coin)[row * TLEN + tm1];
            s_tok[row] = cn ? mi : lab;
        }
        if (cb == 0) {
            float M = -3.0e38f, S = 0.f, L = -INFINITY;
            for (int ib = slot; ib < NLB; ib += 32) {
                int e = row * SSTRIDE + ib;
                float pm = part[e], ps = part[PSTRIDE + e];
                float nM = fmaxf(M, pm);
                S = S * expf(M - nM) + ps * expf(pm - nM);
                M = nM;
                L = fmaxf(L, part[3 * PSTRIDE + e]);
            }
            #pragma unroll
            for (int d = 1; d < 32; d <<= 1) {
                float oM = __shfl_xor(M, d), oS = __shfl_xor(S, d);
                float nM = fmaxf(M, oM);
                S = S * expf(M - nM) + oS * expf(oM - nM);
                M = nM;
                L = fmaxf(L, __shfl_xor(L, d));
            }
            if (slot == 0) ce_acc[row] += (M + logf(S)) - L;
        }
    }
    __syncthreads();

    // ---- PHASE B ----
    int r = lane & 31;
    int ksub = (lane >> 5) << 3;       // 0 or 8
    const bf16x8* wp = (const bf16x8*)wcell + ((size_t)cb * 64 + wv * 4) * 64 + lane;

    f32x16 acc = {};
    if (wv < 8) {
        int tok = s_tok[r];
        if (embbf) {
            const unsigned short* eb = embbf + (size_t)tok * EMBD;
            #pragma unroll
            for (int i = 0; i < 4; ++i) {
                int k = (wv * 4 + i) * 16 + ksub;
                bf16x8 a = *(const bf16x8*)&eb[k];
                acc = __builtin_amdgcn_mfma_f32_32x32x16_bf16(a, wp[i * 64], acc, 0, 0, 0);
            }
        } else {
            const float* ebase = emb + (size_t)tok * EMBD;
            #pragma unroll
            for (int i = 0; i < 4; ++i) {
                int k = (wv * 4 + i) * 16 + ksub;
                float4 e0 = *(const float4*)(ebase + k);
                float4 e1 = *(const float4*)(ebase + k + 4);
                bf16x8 a;
                a[0] = (short)f2bf(e0.x); a[1] = (short)f2bf(e0.y);
                a[2] = (short)f2bf(e0.z); a[3] = (short)f2bf(e0.w);
                a[4] = (short)f2bf(e1.x); a[5] = (short)f2bf(e1.y);
                a[6] = (short)f2bf(e1.z); a[7] = (short)f2bf(e1.w);
                acc = __builtin_amdgcn_mfma_f32_32x32x16_bf16(a, wp[i * 64], acc, 0, 0, 0);
            }
        }
    } else {
        #pragma unroll
        for (int i = 0; i < 4; ++i) {
            int k = (wv * 4 + i) * 16 + ksub - 512;
            bf16x8 a = *(const bf16x8*)&hbf[r * HIDD + k];
            acc = __builtin_amdgcn_mfma_f32_32x32x16_bf16(a, wp[i * 64], acc, 0, 0, 0);
        }
    }

    int half = lane >> 5;
    #pragma unroll
    for (int reg = 0; reg < 16; ++reg) {
        int row = (reg & 3) + 8 * (reg >> 2) + 4 * half;
        sg[wv][row][lane & 31] = acc[reg];
    }
    __syncthreads();

    {
        int row = tid >> 5, lc = tid & 31;
        float s = 0.f;
        #pragma unroll
        for (int w = 0; w < 16; ++w) s += sg[w][row][lc];
        st[row][lc] = s;
    }
    __syncthreads();

    // ---- PHASE C ----
    if (tid < 256) {
        int rr = tid >> 3, jj = tid & 7;
        int jh = cb * 8 + jj;
        float i_ = bias[jh]        + st[rr][jj];
        float f_ = bias[jh + 512]  + st[rr][jj + 8];
        float g_ = bias[jh + 1024] + st[rr][jj + 16];
        float o_ = bias[jh + 1536] + st[rr][jj + 24];
        int idx = rr * HIDD + jh;
        float ci = cst[idx];
        float cn = sigmoidf_(f_) * ci + sigmoidf_(i_) * tanhf(g_);
        float hn = sigmoidf_(o_) * tanhf(cn);
        cst[idx] = cn;
        hbf[idx] = f2bf(hn);
        hf8[idx] = f2e4m3(hn * SH);
    }
}

// ---------------------------------------------------------------------------
// logits_fp8c: 500 blocks x 512 thr (2 blocks/CU co-res = 4 waves/SIMD).
// Block = 2 col-groups (g = blk*2 + p) x 4 K-quarters (kq). Wave (p,kq):
// prefetch 4 ulonglong2 wot loads -> 8 MFMAs (2 chains). kq>0 waves write
// partials to sacc[p][kq-1]; kq==0 waves combine + R13-proven epilogue;
// tid<32 merges the 2 ordered groups -> part slot blockIdx (stride 512).
// C/D layout: col=lane&31, row=(reg&3)+8*(reg>>2)+4*(lane>>5).
// ---------------------------------------------------------------------------
__global__ __launch_bounds__(512, 4) void logits_fp8c_kernel(
    const i64* __restrict__ wot8, const unsigned char* __restrict__ h_f8,
    const float* __restrict__ bo, const int* __restrict__ labels,
    float* __restrict__ part, int t) {
    __shared__ __align__(16) i64 s_h[2048];    // 16 KB paired frag-order
    __shared__ float sacc[2][3][64][17];       // 26.1 KB K-quarter partials
    __shared__ int s_lab[32];
    __shared__ float s_pm[2][32], s_ps[2][32], s_pl[2][32], s_pst[2][32];
    __shared__ int s_pi[2][32];
    int tid = threadIdx.x;
    int lane = tid & 63, wv = tid >> 6;
    int p = wv & 1, kq = wv >> 1;

    // stage h_f8 in paired layout: idx = (kt>>1)*128 + ln*2 + (kt&1)
    for (int f = tid; f < 2048; f += 512) {
        int kt = f >> 6, ln = f & 63;
        int row = ln & 31, kb = kt * 16 + ((ln >> 5) << 3);
        s_h[(kt >> 1) * 128 + ln * 2 + (kt & 1)] = *(const i64*)&h_f8[row * 512 + kb];
    }
    if (tid < 32) s_lab[tid] = labels[tid * TLEN + t];
    __syncthreads();

    int g = blockIdx.x * 2 + p;                 // col-group 0..999
    const ulonglong2* wp16 = (const ulonglong2*)(wot8 + (size_t)g * 2048) + lane;
    const ulonglong2* sh16 = (const ulonglong2*)s_h + lane;

    ulonglong2 wq[4];
    #pragma unroll
    for (int i = 0; i < 4; ++i) wq[i] = wp16[(kq * 4 + i) * 64];   // 4 in flight

    f32x16 acc0 = {}, acc1 = {};
    #pragma unroll
    for (int i = 0; i < 4; ++i) {
        ulonglong2 ah = sh16[(kq * 4 + i) * 64];
        acc0 = __builtin_amdgcn_mfma_f32_32x32x16_fp8_fp8(
            (i64)ah.x, (i64)wq[i].x, acc0, 0, 0, 0);
        acc1 = __builtin_amdgcn_mfma_f32_32x32x16_fp8_fp8(
            (i64)ah.y, (i64)wq[i].y, acc1, 0, 0, 0);
    }

    if (kq > 0) {
        #pragma unroll
        for (int reg = 0; reg < 16; ++reg)
            sacc[p][kq - 1][lane][reg] = acc0[reg] + acc1[reg];
    }
    __syncthreads();

    if (kq == 0) {
        int half = lane >> 5;
        int colw = lane & 31;
        int col = g * 32 + colw;
        float bq = bo[col];
        #pragma unroll
        for (int reg = 0; reg < 16; ++reg) {
            int row = (reg & 3) + 8 * (reg >> 2) + 4 * half;
            float v = (acc0[reg] + acc1[reg] + sacc[p][0][lane][reg]
                       + sacc[p][1][lane][reg] + sacc[p][2][lane][reg])
                      * INV_SWH + bq;
            float m = v; int mi = col;
            #pragma unroll
            for (int d = 1; d < 32; d <<= 1) {
                float om = __shfl_xor(m, d);
                int omi = __shfl_xor(mi, d);
                if (om > m || (om == m && omi < mi)) { m = om; mi = omi; }
            }
            float e = expf(v - m), ssum = e;
            #pragma unroll
            for (int d = 1; d < 32; d <<= 1) ssum += __shfl_xor(ssum, d);
            int labc = s_lab[row];
            float lv = __shfl(v, (labc & 31) + (half << 5));
            if ((labc >> 5) != g) lv = -INFINITY;
            float sv = __shfl(v, 2 + (half << 5));   // STOP = 2
            if (g != 0) sv = -INFINITY;
            if (colw == 0) {
                s_pm[p][row] = m; s_ps[p][row] = ssum; s_pi[p][row] = mi;
                s_pl[p][row] = lv; s_pst[p][row] = sv;
            }
        }
    }
    __syncthreads();

    if (tid < 32) {
        int row = tid;
        float M = s_pm[0][row], S = s_ps[0][row];
        int MI = s_pi[0][row];
        float L = s_pl[0][row], ST = s_pst[0][row];
        {   // merge group p=1 (higher col indices; strict > keeps low-index ties)
            float pm = s_pm[1][row], ps = s_ps[1][row];
            int pi = s_pi[1][row];
            float nM = fmaxf(M, pm);
            S = S * expf(M - nM) + ps * expf(pm - nM);
            if (pm > M || (pm == M && pi < MI)) MI = pi;
            M = nM;
            L = fmaxf(L, s_pl[1][row]);
            ST = fmaxf(ST, s_pst[1][row]);
        }
        int e0 = row * SSTRIDE + blockIdx.x;
        part[e0] = M;
        part[PSTRIDE + e0] = S;
        part[2 * PSTRIDE + e0] = __int_as_float(MI);
        part[3 * PSTRIDE + e0] = L;
        part[4 * PSTRIDE + e0] = ST;
    }
}

// ---------------------------------------------------------------------------
// finalize5 (R13-verified; 500-slot constants): STOP-step CE; out.
// ---------------------------------------------------------------------------
__global__ __launch_bounds__(256) void finalize5_kernel(
    const float* __restrict__ part, const float* __restrict__ ce_acc,
    float* __restrict__ out) {
    __shared__ float s_ce[32];
    int tid = threadIdx.x;
    int row = tid >> 3, slot = tid & 7;
    float M = -3.0e38f, S = 0.f, ST = -INFINITY;
    for (int ib = slot; ib < NLB; ib += 8) {
        int e = row * SSTRIDE + ib;
        float pm = part[e], ps = part[PSTRIDE + e];
        float nM = fmaxf(M, pm);
        S = S * expf(M - nM) + ps * expf(pm - nM);
        M = nM;
        ST = fmaxf(ST, part[4 * PSTRIDE + e]);
    }
    #pragma unroll
    for (int d = 1; d < 8; d <<= 1) {
        float oM = __shfl_xor(M, d), oS = __shfl_xor(S, d);
        float nM = fmaxf(M, oM);
        S = S * expf(M - nM) + oS * expf(oM - nM);
        M = nM;
        ST = fmaxf(ST, __shfl_xor(ST, d));
    }
    if (slot == 0) s_ce[row] = ce_acc[row] + (M + logf(S)) - ST;
    __syncthreads();
    if (tid == 0) {
        float tot = 0.f;
        for (int r = 0; r < 32; ++r) tot += s_ce[r];
        *out = tot / 32.f;
    }
}

// ===========================================================================
extern "C" void kernel_launch(void* const* d_in, const int* in_sizes, int n_in,
                              void* d_out, int out_size, void* d_ws, size_t ws_size,
                              hipStream_t stream) {
    const float* x      = (const float*)d_in[0];
    const int*   labels = (const int*)  d_in[1];
    const void*  coin   =               d_in[2];
    const float* emb    = (const float*)d_in[3];
    const float* Wi     = (const float*)d_in[4];
    const float* Wh     = (const float*)d_in[5];
    const float* b      = (const float*)d_in[6];
    const float* Wo     = (const float*)d_in[7];
    const float* bo     = (const float*)d_in[8];

    float* ws     = (float*)d_ws;
    float* cst    = ws;                        // 16384
    unsigned short* h_bf = (unsigned short*)(ws + 16384);   // 8192 floats
    unsigned char*  h_f8 = (unsigned char*)(ws + 24576);    // 4096 floats
    float* part   = ws + 28672;                // 5*16384 = 81920
    float* ce_acc = ws + 110592;               // 32
    int*   flag   = (int*)(ws + 110624);       // 1 (+pad)
    unsigned short* wcell = (unsigned short*)(ws + 110656); // 1048576 floats
    i64*   wot8   = (i64*)(ws + 110656 + 1048576);          // 4096000 floats
    unsigned short* embbf = (unsigned short*)(ws + 110656 + 1048576 + 4096000); // 8192000 floats
    float* outp   = (float*)d_out;

    size_t need_emb = (size_t)(110656 + 1048576 + 4096000 + 8192000) * 4;
    const unsigned short* embbf_use = (ws_size >= need_emb) ? embbf : (const unsigned short*)0;

    wot8_prep_kernel<<<NGRP, 256, 0, stream>>>(Wo, wot8);
    wcell_prep_kernel<<<128, 256, 0, stream>>>(Wi, Wh, wcell);
    if (embbf_use)
        emb_prep_kernel<<<VOCABSZ * EMBD / 2048, 256, 0, stream>>>(emb, embbf);
    init7_kernel<<<64, 256, 0, stream>>>(x, coin, cst, h_bf, h_f8, ce_acc, flag);

    for (int t = 0; t < 33; ++t) {
        int tt = (t < 32) ? t : 0;
        cell_mfma4_kernel<<<64, 1024, 0, stream>>>(emb, embbf_use, labels, coin,
                                                   flag, wcell, b, cst, h_bf,
                                                   h_f8, part, ce_acc, t);
        logits_fp8c_kernel<<<NLB, 512, 0, stream>>>(wot8, h_f8, bo, labels,
                                                    part, tt);
    }
    finalize5_kernel<<<1, 256, 0, stream>>>(part, ce_acc, outp);
}

// Round 17
// 1070.321 us; speedup vs baseline: 1.1968x; 1.1968x over previous
//
#include <hip/hip_runtime.h>
#include <math.h>

#define VOCABSZ 32000
#define EMBD 512
#define HIDD 512
#define BSZ 32
#define TLEN 32
#define G4 2048
#define NGRP 1000            // wot col-groups of 32
#define NLB 250              // logits blocks / partial slots
#define PSTRIDE 8192         // part SoA stride (32 rows * 256 slots)
#define SW 256.0f            // Wo fp8 scale
#define SH 16.0f             // h fp8 scale
#define INV_SWH (1.0f / (SW * SH))

using bf16x8 = __attribute__((ext_vector_type(8))) short;
using f32x16 = __attribute__((ext_vector_type(16))) float;
typedef long long i64;

__device__ __forceinline__ float sigmoidf_(float x) { return 1.f / (1.f + expf(-x)); }
__device__ __forceinline__ unsigned short f2bf(float f) {
    unsigned u = __float_as_uint(f);
    return (unsigned short)((u + 0x7fffu + ((u >> 16) & 1u)) >> 16);   // RNE
}
// float -> OCP e4m3fn, RNE, FTZ for |x| < 2^-6 (negligible for our data)
__device__ __forceinline__ unsigned char f2e4m3(float f) {
    unsigned u = __float_as_uint(f);
    unsigned s = (u >> 24) & 0x80u;
    int e = (int)((u >> 23) & 0xffu);
    unsigned m = u & 0x7fffffu;
    int ee = e - 120;                    // e4m3 biased exponent
    if (ee >= 16) return (unsigned char)(s | 0x7E);   // saturate to 448
    if (ee <= 0) return (unsigned char)s;             // FTZ
    unsigned r = m + 0x7FFFFu + ((m >> 20) & 1u);     // RNE to 3 mant bits
    if (r & 0x800000u) { ee += 1; r = 0; if (ee >= 16) return (unsigned char)(s | 0x7E); }
    unsigned mant = (r >> 20) & 7u;
    if (ee == 15 && mant == 7u) return (unsigned char)(s | 0x7E);  // avoid NaN enc
    return (unsigned char)(s | (unsigned)(ee << 3) | mant);
}

// ---------------------------------------------------------------------------
// init7 (R15-verified): 64 blocks x 256 thr; block 0 probes coin + ce_acc.
// ---------------------------------------------------------------------------
__global__ __launch_bounds__(256) void init7_kernel(
    const float* __restrict__ x, const void* __restrict__ coin,
    float* __restrict__ cst, unsigned short* __restrict__ hbf,
    unsigned char* __restrict__ hf8,
    float* __restrict__ ce_acc, int* __restrict__ flag) {
    __shared__ int s_f;
    int tid = threadIdx.x;
    int i = blockIdx.x * 256 + tid;
    if (blockIdx.x == 0) {
        if (tid == 0) s_f = 0;
        __syncthreads();
        // coin dtype probe: uint8 bools pack to words like 0x00010001 (>1)
        if (((const unsigned int*)coin)[tid] > 1u) s_f = 1;
        __syncthreads();
        if (tid == 0) *flag = s_f;
        if (tid < 32) ce_acc[tid] = 0.f;
    }
    float v = x[i];
    cst[i] = 0.f;
    hbf[i] = f2bf(v);
    hf8[i] = f2e4m3(v * SH);
}

// ---------------------------------------------------------------------------
// emb_prep (R14-verified): emb fp32 -> bf16 same layout.
// ---------------------------------------------------------------------------
__global__ __launch_bounds__(256) void emb_prep_kernel(
    const float* __restrict__ emb, unsigned short* __restrict__ embbf) {
    size_t i8 = ((size_t)blockIdx.x * 256 + threadIdx.x) * 8;
    float4 a = *(const float4*)&emb[i8];
    float4 b = *(const float4*)&emb[i8 + 4];
    bf16x8 v;
    v[0] = (short)f2bf(a.x); v[1] = (short)f2bf(a.y);
    v[2] = (short)f2bf(a.z); v[3] = (short)f2bf(a.w);
    v[4] = (short)f2bf(b.x); v[5] = (short)f2bf(b.y);
    v[6] = (short)f2bf(b.z); v[7] = (short)f2bf(b.w);
    *(bf16x8*)&embbf[i8] = v;
}

// ---------------------------------------------------------------------------
// wot8_prep (R15-verified): Wo -> e4m3(Wo*SW), B-frag order, PAIRED-kt:
//   flat idx = (kt>>1)*128 + lane*2 + (kt&1)  (per col-group g)
// ---------------------------------------------------------------------------
__global__ __launch_bounds__(256) void wot8_prep_kernel(
    const float* __restrict__ Wo, i64* __restrict__ wot8) {
    __shared__ unsigned char s[512 * 32];      // [k][col] 16 KB
    int g = blockIdx.x;
    int tid = threadIdx.x;
    int col = tid & 31;
    int k0 = tid >> 5;
    for (int kk = k0; kk < 512; kk += 8)
        s[kk * 32 + col] = f2e4m3(Wo[(size_t)kk * VOCABSZ + g * 32 + col] * SW);
    __syncthreads();
    for (int f = tid; f < 2048; f += 256) {
        int kt = f >> 6, lane = f & 63;
        int kb = kt * 16 + ((lane >> 5) << 3);
        int c = lane & 31;
        union { unsigned char b[8]; i64 v; } u;
        #pragma unroll
        for (int j = 0; j < 8; ++j) u.b[j] = s[(kb + j) * 32 + c];
        wot8[(size_t)g * 2048 + (kt >> 1) * 128 + lane * 2 + (kt & 1)] = u.v;
    }
}

// ---------------------------------------------------------------------------
// wcell_prep (R11-R16 verified): Wi/Wh -> bf16 B-frag order block-packed.
// ---------------------------------------------------------------------------
__global__ __launch_bounds__(256) void wcell_prep_kernel(
    const float* __restrict__ Wi, const float* __restrict__ Wh,
    unsigned short* __restrict__ wcell) {
    __shared__ unsigned short s[512 * 32];     // [kl][lc] 32 KB
    int cb = blockIdx.x >> 1;
    int half = blockIdx.x & 1;
    const float* Wsrc = half ? Wh : Wi;
    int tid = threadIdx.x;
    int lc = tid & 31;
    int gcol = (lc >> 3) * 512 + cb * 8 + (lc & 7);
    int k0 = tid >> 5;
    for (int kl = k0; kl < 512; kl += 8)
        s[kl * 32 + lc] = f2bf(Wsrc[(size_t)kl * G4 + gcol]);
    __syncthreads();
    bf16x8* out8 = (bf16x8*)wcell;
    for (int f = tid; f < 2048; f += 256) {
        int ktl = f >> 6, lane = f & 63;
        int kb = ktl * 16 + ((lane >> 5) << 3);
        int c = lane & 31;
        bf16x8 v;
        #pragma unroll
        for (int j = 0; j < 8; ++j) v[j] = (short)s[(kb + j) * 32 + c];
        out8[((size_t)cb * 64 + half * 32 + ktl) * 64 + lane] = v;
    }
}

// ---------------------------------------------------------------------------
// cell_mfma4 (R14/R15-verified, 250-slot constants): 64 blocks x 1024 thr.
// ---------------------------------------------------------------------------
__global__ __launch_bounds__(1024) void cell_mfma4_kernel(
    const float* __restrict__ emb, const unsigned short* __restrict__ embbf,
    const int* __restrict__ labels,
    const void* __restrict__ coin, const int* __restrict__ flag,
    const unsigned short* __restrict__ wcell, const float* __restrict__ bias,
    float* __restrict__ cst, unsigned short* __restrict__ hbf,
    unsigned char* __restrict__ hf8,
    const float* __restrict__ part, float* __restrict__ ce_acc, int t) {
    __shared__ float sg[16][32][32];    // 64 KB [wave][row][lc]
    __shared__ float st[32][33];        // combined gates
    __shared__ int s_tok[32];
    int tid = threadIdx.x;
    int cb = blockIdx.x;
    int lane = tid & 63, wv = tid >> 6;

    // ---- PHASE A ----
    if (t == 0) {
        if (tid < 32) s_tok[tid] = 1;            // START
    } else {
        int row = tid >> 5, slot = tid & 31;
        int tm1 = t - 1;
        float m = -3.0e38f; int mi = 0;
        for (int ib = slot; ib < NLB; ib += 32) {
            int e = row * 256 + ib;
            float pm = part[e];
            int pi = __float_as_int(part[2 * PSTRIDE + e]);
            if (pm > m || (pm == m && pi < mi)) { m = pm; mi = pi; }
        }
        #pragma unroll
        for (int d = 1; d < 32; d <<= 1) {
            float om = __shfl_xor(m, d);
            int omi = __shfl_xor(mi, d);
            if (om > m || (om == m && omi < mi)) { m = om; mi = omi; }
        }
        if (slot == 0) {
            int lab = labels[row * TLEN + tm1];
            int cn = (*flag) ? (int)((const unsigned char*)coin)[row * TLEN + tm1]
                             : ((const int*)coin)[row * TLEN + tm1];
            s_tok[row] = cn ? mi : lab;
        }
        if (cb == 0) {
            float M = -3.0e38f, S = 0.f, L = -INFINITY;
            for (int ib = slot; ib < NLB; ib += 32) {
                int e = row * 256 + ib;
                float pm = part[e], ps = part[PSTRIDE + e];
                float nM = fmaxf(M, pm);
                S = S * expf(M - nM) + ps * expf(pm - nM);
                M = nM;
                L = fmaxf(L, part[3 * PSTRIDE + e]);
            }
            #pragma unroll
            for (int d = 1; d < 32; d <<= 1) {
                float oM = __shfl_xor(M, d), oS = __shfl_xor(S, d);
                float nM = fmaxf(M, oM);
                S = S * expf(M - nM) + oS * expf(oM - nM);
                M = nM;
                L = fmaxf(L, __shfl_xor(L, d));
            }
            if (slot == 0) ce_acc[row] += (M + logf(S)) - L;
        }
    }
    __syncthreads();

    // ---- PHASE B ----
    int r = lane & 31;
    int ksub = (lane >> 5) << 3;       // 0 or 8
    const bf16x8* wp = (const bf16x8*)wcell + ((size_t)cb * 64 + wv * 4) * 64 + lane;

    f32x16 acc = {};
    if (wv < 8) {
        int tok = s_tok[r];
        if (embbf) {
            const unsigned short* eb = embbf + (size_t)tok * EMBD;
            #pragma unroll
            for (int i = 0; i < 4; ++i) {
                int k = (wv * 4 + i) * 16 + ksub;
                bf16x8 a = *(const bf16x8*)&eb[k];
                acc = __builtin_amdgcn_mfma_f32_32x32x16_bf16(a, wp[i * 64], acc, 0, 0, 0);
            }
        } else {
            const float* ebase = emb + (size_t)tok * EMBD;
            #pragma unroll
            for (int i = 0; i < 4; ++i) {
                int k = (wv * 4 + i) * 16 + ksub;
                float4 e0 = *(const float4*)(ebase + k);
                float4 e1 = *(const float4*)(ebase + k + 4);
                bf16x8 a;
                a[0] = (short)f2bf(e0.x); a[1] = (short)f2bf(e0.y);
                a[2] = (short)f2bf(e0.z); a[3] = (short)f2bf(e0.w);
                a[4] = (short)f2bf(e1.x); a[5] = (short)f2bf(e1.y);
                a[6] = (short)f2bf(e1.z); a[7] = (short)f2bf(e1.w);
                acc = __builtin_amdgcn_mfma_f32_32x32x16_bf16(a, wp[i * 64], acc, 0, 0, 0);
            }
        }
    } else {
        #pragma unroll
        for (int i = 0; i < 4; ++i) {
            int k = (wv * 4 + i) * 16 + ksub - 512;
            bf16x8 a = *(const bf16x8*)&hbf[r * HIDD + k];
            acc = __builtin_amdgcn_mfma_f32_32x32x16_bf16(a, wp[i * 64], acc, 0, 0, 0);
        }
    }

    int half = lane >> 5;
    #pragma unroll
    for (int reg = 0; reg < 16; ++reg) {
        int row = (reg & 3) + 8 * (reg >> 2) + 4 * half;
        sg[wv][row][lane & 31] = acc[reg];
    }
    __syncthreads();

    {
        int row = tid >> 5, lc = tid & 31;
        float s = 0.f;
        #pragma unroll
        for (int w = 0; w < 16; ++w) s += sg[w][row][lc];
        st[row][lc] = s;
    }
    __syncthreads();

    // ---- PHASE C ----
    if (tid < 256) {
        int rr = tid >> 3, jj = tid & 7;
        int jh = cb * 8 + jj;
        float i_ = bias[jh]        + st[rr][jj];
        float f_ = bias[jh + 512]  + st[rr][jj + 8];
        float g_ = bias[jh + 1024] + st[rr][jj + 16];
        float o_ = bias[jh + 1536] + st[rr][jj + 24];
        int idx = rr * HIDD + jh;
        float ci = cst[idx];
        float cn = sigmoidf_(f_) * ci + sigmoidf_(i_) * tanhf(g_);
        float hn = sigmoidf_(o_) * tanhf(cn);
        cst[idx] = cn;
        hbf[idx] = f2bf(hn);
        hf8[idx] = f2e4m3(hn * SH);
    }
}

// ---------------------------------------------------------------------------
// logits_fp8b (R15-verified structure + 8-deep wot reg prefetch):
// 250 blocks x 512 thr. Wave wv: col-group p = wv&3 (g = blk*4+p), K-half
// kh = wv>>2. Prefetch all 8 ulonglong2 wot loads, then 16 MFMAs (2 chains).
// K-halves combined via LDS sacc; kh==0 waves run epilogue; tid<32 merges
// 4 ordered groups -> part slot blockIdx (stride 256).
// C/D layout: col=lane&31, row=(reg&3)+8*(reg>>2)+4*(lane>>5).
// ---------------------------------------------------------------------------
__global__ __launch_bounds__(512, 4) void logits_fp8b_kernel(
    const i64* __restrict__ wot8, const unsigned char* __restrict__ h_f8,
    const float* __restrict__ bo, const int* __restrict__ labels,
    float* __restrict__ part, int t) {
    __shared__ __align__(16) i64 s_h[2048];    // 16 KB paired frag-order
    __shared__ float sacc[4][64][17];          // 17.4 KB K-half partials
    __shared__ int s_lab[32];
    __shared__ float s_pm[4][32], s_ps[4][32], s_pl[4][32], s_pst[4][32];
    __shared__ int s_pi[4][32];
    int tid = threadIdx.x;
    int lane = tid & 63, wv = tid >> 6;
    int p = wv & 3, kh = wv >> 2;

    // stage h_f8 in paired layout: idx = (kt>>1)*128 + ln*2 + (kt&1)
    for (int f = tid; f < 2048; f += 512) {
        int kt = f >> 6, ln = f & 63;
        int row = ln & 31, kb = kt * 16 + ((ln >> 5) << 3);
        s_h[(kt >> 1) * 128 + ln * 2 + (kt & 1)] = *(const i64*)&h_f8[row * 512 + kb];
    }
    if (tid < 32) s_lab[tid] = labels[tid * TLEN + t];
    __syncthreads();

    int g = blockIdx.x * 4 + p;                 // col-group 0..999
    const ulonglong2* wp16 = (const ulonglong2*)(wot8 + (size_t)g * 2048) + lane;
    const ulonglong2* sh16 = (const ulonglong2*)s_h + lane;

    // 8-deep register prefetch of wot (all loads in flight before MFMA)
    ulonglong2 wq[8];
    #pragma unroll
    for (int i = 0; i < 8; ++i) wq[i] = wp16[(kh * 8 + i) * 64];

    f32x16 acc0 = {}, acc1 = {};
    #pragma unroll
    for (int i = 0; i < 8; ++i) {
        ulonglong2 ah = sh16[(kh * 8 + i) * 64];
        acc0 = __builtin_amdgcn_mfma_f32_32x32x16_fp8_fp8(
            (i64)ah.x, (i64)wq[i].x, acc0, 0, 0, 0);
        acc1 = __builtin_amdgcn_mfma_f32_32x32x16_fp8_fp8(
            (i64)ah.y, (i64)wq[i].y, acc1, 0, 0, 0);
    }

    if (kh == 1) {
        #pragma unroll
        for (int reg = 0; reg < 16; ++reg)
            sacc[p][lane][reg] = acc0[reg] + acc1[reg];
    }
    __syncthreads();

    if (kh == 0) {
        int half = lane >> 5;
        int colw = lane & 31;
        int col = g * 32 + colw;
        float bq = bo[col];
        #pragma unroll
        for (int reg = 0; reg < 16; ++reg) {
            int row = (reg & 3) + 8 * (reg >> 2) + 4 * half;
            float v = (acc0[reg] + acc1[reg] + sacc[p][lane][reg]) * INV_SWH + bq;
            float m = v; int mi = col;
            #pragma unroll
            for (int d = 1; d < 32; d <<= 1) {
                float om = __shfl_xor(m, d);
                int omi = __shfl_xor(mi, d);
                if (om > m || (om == m && omi < mi)) { m = om; mi = omi; }
            }
            float e = expf(v - m), ssum = e;
            #pragma unroll
            for (int d = 1; d < 32; d <<= 1) ssum += __shfl_xor(ssum, d);
            int labc = s_lab[row];
            float lv = __shfl(v, (labc & 31) + (half << 5));
            if ((labc >> 5) != g) lv = -INFINITY;
            float sv = __shfl(v, 2 + (half << 5));   // STOP = 2
            if (g != 0) sv = -INFINITY;
            if (colw == 0) {
                s_pm[p][row] = m; s_ps[p][row] = ssum; s_pi[p][row] = mi;
                s_pl[p][row] = lv; s_pst[p][row] = sv;
            }
        }
    }
    __syncthreads();

    if (tid < 32) {
        int row = tid;
        float M = s_pm[0][row], S = s_ps[0][row];
        int MI = s_pi[0][row];
        float L = s_pl[0][row], ST = s_pst[0][row];
        #pragma unroll
        for (int w = 1; w < 4; ++w) {
            float pm = s_pm[w][row], ps = s_ps[w][row];
            int pi = s_pi[w][row];
            float nM = fmaxf(M, pm);
            S = S * expf(M - nM) + ps * expf(pm - nM);
            if (pm > M || (pm == M && pi < MI)) MI = pi;
            M = nM;
            L = fmaxf(L, s_pl[w][row]);
            ST = fmaxf(ST, s_pst[w][row]);
        }
        int e0 = row * 256 + blockIdx.x;
        part[e0] = M;
        part[PSTRIDE + e0] = S;
        part[2 * PSTRIDE + e0] = __int_as_float(MI);
        part[3 * PSTRIDE + e0] = L;
        part[4 * PSTRIDE + e0] = ST;
    }
}

// ---------------------------------------------------------------------------
// finalize5 (R13/R15-verified): STOP-step CE; out = (ce_acc + final)/32
// ---------------------------------------------------------------------------
__global__ __launch_bounds__(256) void finalize5_kernel(
    const float* __restrict__ part, const float* __restrict__ ce_acc,
    float* __restrict__ out) {
    __shared__ float s_ce[32];
    int tid = threadIdx.x;
    int row = tid >> 3, slot = tid & 7;
    float M = -3.0e38f, S = 0.f, ST = -INFINITY;
    for (int ib = slot; ib < NLB; ib += 8) {
        int e = row * 256 + ib;
        float pm = part[e], ps = part[PSTRIDE + e];
        float nM = fmaxf(M, pm);
        S = S * expf(M - nM) + ps * expf(pm - nM);
        M = nM;
        ST = fmaxf(ST, part[4 * PSTRIDE + e]);
    }
    #pragma unroll
    for (int d = 1; d < 8; d <<= 1) {
        float oM = __shfl_xor(M, d), oS = __shfl_xor(S, d);
        float nM = fmaxf(M, oM);
        S = S * expf(M - nM) + oS * expf(oM - nM);
        M = nM;
        ST = fmaxf(ST, __shfl_xor(ST, d));
    }
    if (slot == 0) s_ce[row] = ce_acc[row] + (M + logf(S)) - ST;
    __syncthreads();
    if (tid == 0) {
        float tot = 0.f;
        for (int r = 0; r < 32; ++r) tot += s_ce[r];
        *out = tot / 32.f;
    }
}

// ===========================================================================
extern "C" void kernel_launch(void* const* d_in, const int* in_sizes, int n_in,
                              void* d_out, int out_size, void* d_ws, size_t ws_size,
                              hipStream_t stream) {
    const float* x      = (const float*)d_in[0];
    const int*   labels = (const int*)  d_in[1];
    const void*  coin   =               d_in[2];
    const float* emb    = (const float*)d_in[3];
    const float* Wi     = (const float*)d_in[4];
    const float* Wh     = (const float*)d_in[5];
    const float* b      = (const float*)d_in[6];
    const float* Wo     = (const float*)d_in[7];
    const float* bo     = (const float*)d_in[8];

    float* ws     = (float*)d_ws;
    float* cst    = ws;                        // 16384
    unsigned short* h_bf = (unsigned short*)(ws + 16384);   // 8192 floats
    unsigned char*  h_f8 = (unsigned char*)(ws + 24576);    // 4096 floats
    float* part   = ws + 28672;                // 5*8192 = 40960
    float* ce_acc = ws + 69632;                // 32
    int*   flag   = (int*)(ws + 69664);        // 1 (+pad)
    unsigned short* wcell = (unsigned short*)(ws + 69696);  // 1048576 floats
    i64*   wot8   = (i64*)(ws + 69696 + 1048576);           // 4096000 floats
    unsigned short* embbf = (unsigned short*)(ws + 69696 + 1048576 + 4096000); // 8192000 floats
    float* outp   = (float*)d_out;

    size_t need_emb = (size_t)(69696 + 1048576 + 4096000 + 8192000) * 4;
    const unsigned short* embbf_use = (ws_size >= need_emb) ? embbf : (const unsigned short*)0;

    wot8_prep_kernel<<<NGRP, 256, 0, stream>>>(Wo, wot8);
    wcell_prep_kernel<<<128, 256, 0, stream>>>(Wi, Wh, wcell);
    if (embbf_use)
        emb_prep_kernel<<<VOCABSZ * EMBD / 2048, 256, 0, stream>>>(emb, embbf);
    init7_kernel<<<64, 256, 0, stream>>>(x, coin, cst, h_bf, h_f8, ce_acc, flag);

    for (int t = 0; t < 33; ++t) {
        int tt = (t < 32) ? t : 0;
        cell_mfma4_kernel<<<64, 1024, 0, stream>>>(emb, embbf_use, labels, coin,
                                                   flag, wcell, b, cst, h_bf,
                                                   h_f8, part, ce_acc, t);
        logits_fp8b_kernel<<<NLB, 512, 0, stream>>>(wot8, h_f8, bo, labels,
                                                    part, tt);
    }
    finalize5_kernel<<<1, 256, 0, stream>>>(part, ce_acc, outp);
}